// Round 6
// baseline (486.052 us; speedup 1.0000x reference)
//
#include <hip/hip_runtime.h>
#include <hip/hip_bf16.h>

#define NODES 4097
#define TT 4096
#define CIN 64
#define HID 128
#define BATCH 64
#define EPS 1e-5f

typedef short bf16x8 __attribute__((ext_vector_type(8)));   // 8 bf16 = 4 VGPRs
typedef float f32x16 __attribute__((ext_vector_type(16)));  // 32x32 acc

// async global->LDS DMA, 16 B per lane; LDS dst = wave-uniform base + lane*16
__device__ __forceinline__ void load_lds16(const void* g, void* l) {
    __builtin_amdgcn_global_load_lds(
        (const __attribute__((address_space(1))) unsigned int*)(uintptr_t)g,
        (__attribute__((address_space(3))) unsigned int*)(uintptr_t)l,
        16, 0, 0);
}

// ---------------- transpose feats (B,C,N) fp32 -> fT (B,N,C) bf16, both encoders ----------------
__global__ __launch_bounds__(256) void k_transpose(const float* __restrict__ f0,
                                                   const float* __restrict__ f1,
                                                   __hip_bfloat16* __restrict__ out) {
    __shared__ float tile[32][33];
    int z = blockIdx.z;
    int enc = z >> 6, b = z & 63;
    const float* in = enc ? f1 : f0;
    __hip_bfloat16* o = out + (size_t)enc * BATCH * NODES * CIN;
    int n0 = blockIdx.x * 32;
    int c0 = blockIdx.y * 32;
    int tx = threadIdx.x, ty = threadIdx.y;  // (32,8)
    for (int i = 0; i < 32; i += 8) {
        int n = n0 + tx, c = c0 + ty + i;
        float v = 0.f;
        if (n < NODES) v = in[((size_t)b * CIN + c) * NODES + n];
        tile[ty + i][tx] = v;
    }
    __syncthreads();
    for (int i = 0; i < 32; i += 8) {
        int n = n0 + ty + i, c = c0 + tx;
        if (n < NODES) o[((size_t)b * NODES + n) * CIN + c] = __float2bfloat16(tile[tx][ty + i]);
    }
}

// ---------------- W (HID,C,3) fp32 -> frag-major bf16 B-operand layout, both encoders ----------------
// Wp id = (ks*4 + ct)*64 + lane holds 8 bf16: B[k=ks*16+(lane>>5)*8+j][n=ct*32+(lane&31)]
// k = slot*C + c; B[k][n] = W[(n*C + c)*3 + slot]
__global__ void k_wprep(const float* __restrict__ W0, const float* __restrict__ W1,
                        __hip_bfloat16* __restrict__ Wp, int C) {
    int enc = blockIdx.y;
    const float* W = enc ? W1 : W0;
    __hip_bfloat16* o = Wp + (size_t)enc * 3 * C * HID;
    int id = blockIdx.x * 256 + threadIdx.x;
    int total = 3 * C * HID / 8;
    if (id >= total) return;
    int lane = id & 63;
    int ct = (id >> 6) & 3;
    int ks = id >> 8;
    int n = ct * 32 + (lane & 31);
    int kb = ks * 16 + (lane >> 5) * 8;
    union { int4 i; __hip_bfloat16 h[8]; } u;
#pragma unroll
    for (int j = 0; j < 8; ++j) {
        int k = kb + j;
        int slot = k / C, c = k % C;
        u.h[j] = __float2bfloat16(W[(n * C + c) * 3 + slot]);
    }
    ((int4*)o)[id] = u.i;
}

// ---------------- gather-conv via MFMA + global_load_lds ----------------
// 1-D grid 8192, XCD-swizzled: xcd=L&7, node-tile fastest, b = xcd+8*g pinned per XCD
// block = 256 thr (4 waves), tile = 64 nodes x 128 out-ch; wave w: nodes 32*(w>>1), o 64*(w&1)
// A staged via DMA in lane-linear 1-KB chunks (32 nodes x 1 kstep); chunk (tb,kk) at
// (tb*PK+kk)*1024, lane l -> node (l&31), k-octet (l>>5). Wave stages its own tb=w>>1.
template <int C, int NPH, bool POOL>
__global__ __launch_bounds__(256) void k_conv_mfma(
    const __hip_bfloat16* __restrict__ xT,    // [2][B][N][C]
    const int* __restrict__ children,
    const __hip_bfloat16* __restrict__ Wp,    // [2][3C*HID] frag-major
    const float* __restrict__ bias0, const float* __restrict__ bias1,
    __hip_bfloat16* __restrict__ y,           // [2][B][N][HID] raw out (if !POOL)
    float* __restrict__ sums,                 // [2B][2]
    float* __restrict__ pool_part) {          // [2B][64][HID] (if POOL)
    constexpr int KSc = C / 16;             // ksteps per child-slot
    constexpr int TOTK = 3 * KSc;           // 12 or 24 ksteps
    constexpr int PK = TOTK / NPH;          // ksteps per phase
    // ---- XCD-aware swizzle ----
    int L = blockIdx.x;
    int xcd = L & 7;
    int idx = L >> 3;
    int xt = idx & 63;              // node-tile (fastest within XCD)
    int bg = (idx >> 6) & 7;
    int enc = idx >> 9;
    int b = xcd + 8 * bg;           // b pinned to one XCD -> gather set ~2 MB/XCD
    const int t0 = xt * 64;
    const int tid = threadIdx.x;
    const int lane = tid & 63;
    const int w = tid >> 6;
    const int rg2 = w >> 1, ct2 = w & 1;

    __shared__ __align__(16) char A_lds[2 * PK * 1024];

    const __hip_bfloat16* x = xT + (size_t)enc * BATCH * NODES * C;
    const int4* WpB = (const int4*)(Wp + (size_t)enc * 3 * C * HID);
    const float* bias = enc ? bias1 : bias0;
    const int sb = enc * BATCH + b;

    const size_t rowbase = (size_t)b * NODES;
    const long cb3 = (long)b * (3 * TT);
    const int tnode = t0 + rg2 * 32 + (lane & 31);  // node this lane stages

    // preload the three gathered-row pointers (removes dependent load per phase)
    const char* rowp[3];
#pragma unroll
    for (int s = 0; s < 3; ++s) {
        int child = children[cb3 + (long)tnode * 3 + s];
        rowp[s] = (const char*)(x + (rowbase + child) * C) + (lane >> 5) * 16;
    }

    f32x16 acc[2] = {};

#pragma unroll
    for (int ph = 0; ph < NPH; ++ph) {
        if (ph) __syncthreads();  // prior MFMA reads done before overwrite
#pragma unroll
        for (int i = 0; i < PK / 2; ++i) {
            int kk = (w & 1) * (PK / 2) + i;
            int ksg = ph * PK + kk;
            int slot = ksg / KSc, ksl = ksg % KSc;
            load_lds16(rowp[slot] + ksl * 32, A_lds + (rg2 * PK + kk) * 1024);
        }
        __syncthreads();  // drains DMA (vmcnt) + barrier
#pragma unroll
        for (int kk = 0; kk < PK; ++kk) {
            int ksg = ph * PK + kk;
            bf16x8 a = *(const bf16x8*)(A_lds + (rg2 * PK + kk) * 1024 + lane * 16);
            union { int4 i; bf16x8 v; } b0, b1;
            b0.i = WpB[(ksg * 4 + 2 * ct2 + 0) * 64 + lane];
            b1.i = WpB[(ksg * 4 + 2 * ct2 + 1) * 64 + lane];
            acc[0] = __builtin_amdgcn_mfma_f32_32x32x16_bf16(a, b0.v, acc[0], 0, 0, 0);
            acc[1] = __builtin_amdgcn_mfma_f32_32x32x16_bf16(a, b1.v, acc[1], 0, 0, 0);
        }
    }

    // ---- epilogue: bias, stats, and (POOL ? per-o max : bf16 store) ----
    float bsum = 0.f, bss = 0.f;
    float lmax[2] = {-3.4e38f, -3.4e38f};
    __hip_bfloat16* yp = POOL ? nullptr : (y + (size_t)enc * BATCH * NODES * HID);
#pragma unroll
    for (int cti = 0; cti < 2; ++cti) {
        int o = 64 * ct2 + 32 * cti + (lane & 31);
        float bv = bias[o];
        int rbase = t0 + 32 * rg2 + 4 * (lane >> 5) + 1;
        f32x16 a = acc[cti];
#pragma unroll
        for (int reg = 0; reg < 16; ++reg) {
            float v = a[reg] + bv;
            bsum += v;
            bss += v * v;
            if (POOL) {
                lmax[cti] = fmaxf(lmax[cti], v);
            } else {
                int row = rbase + (reg & 3) + 8 * (reg >> 2);
                yp[(rowbase + row) * HID + o] = __float2bfloat16(v);
            }
        }
    }
    if (!POOL && xt == 0 && tid < HID)
        yp[rowbase * HID + tid] = __float2bfloat16(0.f);

    __syncthreads();  // LDS reads done; reuse as reduction scratch
    float* red = (float*)A_lds;          // [0..511] sum/sumsq
    float* pm = red + 512;               // [512..1023] per-o max slices
    red[tid] = bsum;
    red[256 + tid] = bss;
    if (POOL) {
        int slice = 2 * rg2 + (lane >> 5);
        pm[(64 * ct2 + (lane & 31)) * 4 + slice] = lmax[0];
        pm[(64 * ct2 + 32 + (lane & 31)) * 4 + slice] = lmax[1];
    }
    __syncthreads();
    for (int s2 = 128; s2 > 0; s2 >>= 1) {
        if (tid < s2) { red[tid] += red[tid + s2]; red[256 + tid] += red[256 + tid + s2]; }
        __syncthreads();
    }
    if (tid == 0) {
        atomicAdd(&sums[sb * 2], red[0]);
        atomicAdd(&sums[sb * 2 + 1], red[256]);
    }
    if (POOL && tid < HID) {
        float m = fmaxf(fmaxf(pm[tid * 4], pm[tid * 4 + 1]),
                        fmaxf(pm[tid * 4 + 2], pm[tid * 4 + 3]));
        pool_part[((size_t)sb * 64 + xt) * HID + tid] = m;
    }
}

// ---------------- per-(enc,b) stats: sum,sumsq -> mean, 1/(std+eps) ----------------
__global__ void k_stats(const float* __restrict__ sums, float* __restrict__ ms) {
    int s = threadIdx.x;  // 128 = 2 enc x 64 b
    const float M = (float)HID * (float)NODES;
    float S = sums[s * 2], SS = sums[s * 2 + 1];
    float mean = S / M;
    float var = (SS - S * S / M) / (M - 1.f);
    float sd = sqrtf(fmaxf(var, 0.f));
    ms[s * 2] = mean;
    ms[s * 2 + 1] = 1.f / (sd + EPS);
}

// ---------------- in-place norm+relu of y1 (bf16 x8 vectorized) ----------------
__global__ __launch_bounds__(256) void k_norm(__hip_bfloat16* __restrict__ y,
                                              const float* __restrict__ ms) {
    constexpr int Q = NODES * HID / 8;  // 65552 int4s per (enc,b) slice
    int s = blockIdx.y;                 // enc*64 + b
    int q = blockIdx.x * 256 + threadIdx.x;
    if (q >= Q) return;
    float mean = ms[s * 2], scale = ms[s * 2 + 1];
    int4* p = (int4*)(y + (size_t)s * NODES * HID) + q;
    union { int4 i; __hip_bfloat16 h[8]; } u;
    u.i = *p;
#pragma unroll
    for (int j = 0; j < 8; ++j) {
        float f = (__bfloat162float(u.h[j]) - mean) * scale;
        u.h[j] = __float2bfloat16(f > 0.f ? f : 0.f);
    }
    *p = u.i;
}

// ---------------- finalize pool: reduce 64 partials, norm+relu ----------------
__global__ __launch_bounds__(128) void k_pool_fin(const float* __restrict__ part,
                                                  const float* __restrict__ ms1,
                                                  float* __restrict__ combined) {
    int b = blockIdx.x, enc = blockIdx.y, o = threadIdx.x;
    int sb = enc * BATCH + b;
    float m = 0.f;  // node-0 raw value is 0
#pragma unroll 4
    for (int s = 0; s < 64; ++s)
        m = fmaxf(m, part[((size_t)sb * 64 + s) * HID + o]);
    float v = (m - ms1[sb * 2]) * ms1[sb * 2 + 1];  // monotone: max then transform
    combined[b * 256 + enc * 128 + o] = v > 0.f ? v : 0.f;
}

// ---------------- final FC: mu / logvar ----------------
__global__ __launch_bounds__(128) void k_fc(const float* __restrict__ combined,
                                            const float* __restrict__ Wmu, const float* __restrict__ bmu,
                                            const float* __restrict__ Wlv, const float* __restrict__ blv,
                                            float* __restrict__ out) {
    int b = blockIdx.x;
    int tid = threadIdx.x;
    __shared__ float cb[256];
    cb[tid] = combined[b * 256 + tid];
    cb[tid + 128] = combined[b * 256 + tid + 128];
    __syncthreads();
    const float* W = (tid < 64) ? Wmu : Wlv;
    int l = tid & 63;
    float s = (tid < 64) ? bmu[l] : blv[l];
    for (int j = 0; j < 256; ++j) s += cb[j] * W[l * 256 + j];
    out[(tid < 64 ? 0 : BATCH * 64) + b * 64 + l] = s;
}

extern "C" void kernel_launch(void* const* d_in, const int* in_sizes, int n_in,
                              void* d_out, int out_size, void* d_ws, size_t ws_size,
                              hipStream_t stream) {
    const int* children = (const int*)d_in[2];
    const float* Wmu = (const float*)d_in[11];
    const float* bmu = (const float*)d_in[12];
    const float* Wlv = (const float*)d_in[13];
    const float* blv = (const float*)d_in[14];

    // ---- workspace layout (256B aligned) ----
    char* ws = (char*)d_ws;
    size_t off = 0;
    auto alloc = [&](size_t bytes) { void* p = ws + off; off += (bytes + 255) & ~(size_t)255; return p; };
    float* sums = (float*)alloc(2 * 2 * BATCH * 2 * sizeof(float));  // [layer][enc*B+b][2]
    float* msbuf = (float*)alloc(2 * 2 * BATCH * 2 * sizeof(float));
    float* combined = (float*)alloc((size_t)BATCH * 256 * sizeof(float));
    float* pool_part = (float*)alloc((size_t)2 * BATCH * 64 * HID * sizeof(float));
    __hip_bfloat16* Wp1 = (__hip_bfloat16*)alloc((size_t)2 * 3 * CIN * HID * sizeof(__hip_bfloat16));
    __hip_bfloat16* Wp2 = (__hip_bfloat16*)alloc((size_t)2 * 3 * HID * HID * sizeof(__hip_bfloat16));
    __hip_bfloat16* fT = (__hip_bfloat16*)alloc((size_t)2 * BATCH * NODES * CIN * sizeof(__hip_bfloat16));
    __hip_bfloat16* y1 = (__hip_bfloat16*)alloc((size_t)2 * BATCH * NODES * HID * sizeof(__hip_bfloat16));

    hipMemsetAsync(sums, 0, 2 * 2 * BATCH * 2 * sizeof(float), stream);

    k_wprep<<<dim3(3 * CIN * HID / 8 / 256, 2), 256, 0, stream>>>(
        (const float*)d_in[3], (const float*)d_in[7], Wp1, CIN);
    k_wprep<<<dim3(3 * HID * HID / 8 / 256, 2), 256, 0, stream>>>(
        (const float*)d_in[5], (const float*)d_in[9], Wp2, HID);
    k_transpose<<<dim3(129, 2, 2 * BATCH), dim3(32, 8), 0, stream>>>(
        (const float*)d_in[0], (const float*)d_in[1], fT);

    k_conv_mfma<CIN, 2, false><<<8192, 256, 0, stream>>>(
        fT, children, Wp1, (const float*)d_in[4], (const float*)d_in[8], y1, sums, nullptr);
    k_stats<<<1, 128, 0, stream>>>(sums, msbuf);
    k_norm<<<dim3((NODES * HID / 8 + 255) / 256, 2 * BATCH), 256, 0, stream>>>(y1, msbuf);
    k_conv_mfma<HID, 3, true><<<8192, 256, 0, stream>>>(
        y1, children, Wp2, (const float*)d_in[6], (const float*)d_in[10], nullptr,
        sums + 256, pool_part);
    k_stats<<<1, 128, 0, stream>>>(sums + 256, msbuf + 256);
    k_pool_fin<<<dim3(BATCH, 2), 128, 0, stream>>>(pool_part, msbuf + 256, combined);

    k_fc<<<BATCH, 128, 0, stream>>>(combined, Wmu, bmu, Wlv, blv, (float*)d_out);
}

// Round 7
// 462.093 us; speedup vs baseline: 1.0519x; 1.0519x over previous
//
#include <hip/hip_runtime.h>
#include <hip/hip_bf16.h>

#define NODES 4097
#define TT 4096
#define CIN 64
#define HID 128
#define BATCH 64
#define EPS 1e-5f

typedef short bf16x8 __attribute__((ext_vector_type(8)));   // 8 bf16 = 4 VGPRs
typedef float f32x16 __attribute__((ext_vector_type(16)));  // 32x32 acc

// ---------------- transpose feats (B,C,N) fp32 -> fT (B,N,C) bf16, both encoders ----------------
__global__ __launch_bounds__(256) void k_transpose(const float* __restrict__ f0,
                                                   const float* __restrict__ f1,
                                                   __hip_bfloat16* __restrict__ out) {
    __shared__ float tile[32][33];
    int z = blockIdx.z;
    int enc = z >> 6, b = z & 63;
    const float* in = enc ? f1 : f0;
    __hip_bfloat16* o = out + (size_t)enc * BATCH * NODES * CIN;
    int n0 = blockIdx.x * 32;
    int c0 = blockIdx.y * 32;
    int tx = threadIdx.x, ty = threadIdx.y;  // (32,8)
    for (int i = 0; i < 32; i += 8) {
        int n = n0 + tx, c = c0 + ty + i;
        float v = 0.f;
        if (n < NODES) v = in[((size_t)b * CIN + c) * NODES + n];
        tile[ty + i][tx] = v;
    }
    __syncthreads();
    for (int i = 0; i < 32; i += 8) {
        int n = n0 + ty + i, c = c0 + tx;
        if (n < NODES) o[((size_t)b * NODES + n) * CIN + c] = __float2bfloat16(tile[tx][ty + i]);
    }
}

// ---------------- W (HID,C,3) fp32 -> frag-major bf16 B-operand layout, both encoders ----------------
// Wp id = (ks*4 + ct)*64 + lane holds 8 bf16: B[k=ks*16+(lane>>5)*8+j][n=ct*32+(lane&31)]
// k = slot*C + c; B[k][n] = W[(n*C + c)*3 + slot]
__global__ void k_wprep(const float* __restrict__ W0, const float* __restrict__ W1,
                        __hip_bfloat16* __restrict__ Wp, int C) {
    int enc = blockIdx.y;
    const float* W = enc ? W1 : W0;
    __hip_bfloat16* o = Wp + (size_t)enc * 3 * C * HID;
    int id = blockIdx.x * 256 + threadIdx.x;
    int total = 3 * C * HID / 8;
    if (id >= total) return;
    int lane = id & 63;
    int ct = (id >> 6) & 3;
    int ks = id >> 8;
    int n = ct * 32 + (lane & 31);
    int kb = ks * 16 + (lane >> 5) * 8;
    union { int4 i; __hip_bfloat16 h[8]; } u;
#pragma unroll
    for (int j = 0; j < 8; ++j) {
        int k = kb + j;
        int slot = k / C, c = k % C;
        u.h[j] = __float2bfloat16(W[(n * C + c) * 3 + slot]);
    }
    ((int4*)o)[id] = u.i;
}

// ---------------- gather-conv via MFMA, A-frags loaded straight to registers ----------------
// Grid 4096 XCD-swizzled (xcd=L&7, node-tile fastest, b=xcd+8*bg pinned per XCD).
// Block = 4 waves; wave w computes nodes [t0+32w, t0+32w+32) x all 128 o.
// A-frag for kstep: lane l <- node (l&31), k-octet (l>>5): ONE per-lane 16B global
// load at row + ksl*32 + (l>>5)*16 — no LDS, no barriers, compiler-pipelined vmcnt.
template <int C, bool POOL>
__global__ __launch_bounds__(256) void k_conv_mfma(
    const __hip_bfloat16* __restrict__ xT,    // [2][B][N][C]
    const int* __restrict__ children,
    const __hip_bfloat16* __restrict__ Wp,    // [2][3C*HID] frag-major
    const float* __restrict__ bias0, const float* __restrict__ bias1,
    __hip_bfloat16* __restrict__ y,           // [2][B][N][HID] raw out (if !POOL)
    float* __restrict__ sums,                 // [2B][2]
    float* __restrict__ pool_part) {          // [2B][32][HID] (if POOL)
    constexpr int KSc = C / 16;             // ksteps per child-slot
    constexpr int KS = 3 * KSc;             // 12 or 24 ksteps total
    // ---- XCD-aware swizzle ----
    int L = blockIdx.x;
    int xcd = L & 7;
    int idx = L >> 3;
    int xt = idx & 31;              // node-tile (fastest within XCD)
    int bg = (idx >> 5) & 7;
    int enc = idx >> 8;
    int b = xcd + 8 * bg;           // b pinned to one XCD -> gather set stays in L2
    const int t0 = xt * 128;
    const int tid = threadIdx.x;
    const int lane = tid & 63;
    const int w = tid >> 6;
    const int hi = lane >> 5;

    const __hip_bfloat16* x = xT + (size_t)enc * BATCH * NODES * C;
    const int4* WpB = (const int4*)(Wp + (size_t)enc * 3 * C * HID);
    const float* bias = enc ? bias1 : bias0;
    const int sb = enc * BATCH + b;
    const size_t rowbase = (size_t)b * NODES;
    const long cb3 = (long)b * (3 * TT);
    const int tnode = t0 + w * 32 + (lane & 31);  // node this lane's A-frags cover

    // gathered-row pointers, offset by this lane's k-octet half
    const int4* ap[3];
#pragma unroll
    for (int s = 0; s < 3; ++s) {
        int child = children[cb3 + (long)tnode * 3 + s];
        ap[s] = (const int4*)(x + (rowbase + child) * C) + hi;
    }

    f32x16 acc[4] = {};
#pragma unroll
    for (int ksg = 0; ksg < KS; ++ksg) {
        int slot = ksg / KSc, ksl = ksg % KSc;
        union { int4 i; bf16x8 v; } a;
        a.i = ap[slot][ksl * 2];
#pragma unroll
        for (int cti = 0; cti < 4; ++cti) {
            union { int4 i; bf16x8 v; } bb;
            bb.i = WpB[(ksg * 4 + cti) * 64 + lane];
            acc[cti] = __builtin_amdgcn_mfma_f32_32x32x16_bf16(a.v, bb.v, acc[cti], 0, 0, 0);
        }
    }

    // ---- epilogue: bias, stats, and (POOL ? per-o max : bf16 store) ----
    __shared__ float red[512];   // sum/sumsq reduction
    __shared__ float pm[1024];   // per-o max slices (POOL)
    float bsum = 0.f, bss = 0.f;
    __hip_bfloat16* yp = POOL ? nullptr : (y + (size_t)enc * BATCH * NODES * HID);
    const int rbase = t0 + w * 32 + 4 * hi + 1;  // +1: node-0 shift
#pragma unroll
    for (int cti = 0; cti < 4; ++cti) {
        int o = cti * 32 + (lane & 31);
        float bv = bias[o];
        f32x16 a = acc[cti];
        float lmax = -3.4e38f;
#pragma unroll
        for (int reg = 0; reg < 16; ++reg) {
            float v = a[reg] + bv;
            bsum += v;
            bss += v * v;
            if (POOL) {
                lmax = fmaxf(lmax, v);
            } else {
                int row = rbase + (reg & 3) + 8 * (reg >> 2);
                yp[(rowbase + row) * HID + o] = __float2bfloat16(v);
            }
        }
        if (POOL) pm[o * 8 + w * 2 + hi] = lmax;
    }
    if (!POOL && xt == 0 && tid < HID)
        yp[rowbase * HID + tid] = __float2bfloat16(0.f);

    red[tid] = bsum;
    red[256 + tid] = bss;
    __syncthreads();
    for (int s2 = 128; s2 > 0; s2 >>= 1) {
        if (tid < s2) { red[tid] += red[tid + s2]; red[256 + tid] += red[256 + tid + s2]; }
        __syncthreads();
    }
    if (tid == 0) {
        atomicAdd(&sums[sb * 2], red[0]);
        atomicAdd(&sums[sb * 2 + 1], red[256]);
    }
    if (POOL && tid < HID) {
        float m = -3.4e38f;
#pragma unroll
        for (int s2 = 0; s2 < 8; ++s2) m = fmaxf(m, pm[tid * 8 + s2]);
        pool_part[((size_t)sb * 32 + xt) * HID + tid] = m;
    }
}

// ---------------- per-(enc,b) stats: sum,sumsq -> mean, 1/(std+eps) ----------------
__global__ void k_stats(const float* __restrict__ sums, float* __restrict__ ms) {
    int s = threadIdx.x;  // 128 = 2 enc x 64 b
    const float M = (float)HID * (float)NODES;
    float S = sums[s * 2], SS = sums[s * 2 + 1];
    float mean = S / M;
    float var = (SS - S * S / M) / (M - 1.f);
    float sd = sqrtf(fmaxf(var, 0.f));
    ms[s * 2] = mean;
    ms[s * 2 + 1] = 1.f / (sd + EPS);
}

// ---------------- in-place norm+relu of y1 (bf16 x8 vectorized) ----------------
__global__ __launch_bounds__(256) void k_norm(__hip_bfloat16* __restrict__ y,
                                              const float* __restrict__ ms) {
    constexpr int Q = NODES * HID / 8;  // 65552 int4s per (enc,b) slice
    int s = blockIdx.y;                 // enc*64 + b
    int q = blockIdx.x * 256 + threadIdx.x;
    if (q >= Q) return;
    float mean = ms[s * 2], scale = ms[s * 2 + 1];
    int4* p = (int4*)(y + (size_t)s * NODES * HID) + q;
    union { int4 i; __hip_bfloat16 h[8]; } u;
    u.i = *p;
#pragma unroll
    for (int j = 0; j < 8; ++j) {
        float f = (__bfloat162float(u.h[j]) - mean) * scale;
        u.h[j] = __float2bfloat16(f > 0.f ? f : 0.f);
    }
    *p = u.i;
}

// ---------------- finalize pool: reduce 32 partials, norm+relu ----------------
__global__ __launch_bounds__(128) void k_pool_fin(const float* __restrict__ part,
                                                  const float* __restrict__ ms1,
                                                  float* __restrict__ combined) {
    int b = blockIdx.x, enc = blockIdx.y, o = threadIdx.x;
    int sb = enc * BATCH + b;
    float m = 0.f;  // node-0 raw value is 0
#pragma unroll 4
    for (int s = 0; s < 32; ++s)
        m = fmaxf(m, part[((size_t)sb * 32 + s) * HID + o]);
    float v = (m - ms1[sb * 2]) * ms1[sb * 2 + 1];  // monotone: max then transform
    combined[b * 256 + enc * 128 + o] = v > 0.f ? v : 0.f;
}

// ---------------- final FC: mu / logvar ----------------
__global__ __launch_bounds__(128) void k_fc(const float* __restrict__ combined,
                                            const float* __restrict__ Wmu, const float* __restrict__ bmu,
                                            const float* __restrict__ Wlv, const float* __restrict__ blv,
                                            float* __restrict__ out) {
    int b = blockIdx.x;
    int tid = threadIdx.x;
    __shared__ float cb[256];
    cb[tid] = combined[b * 256 + tid];
    cb[tid + 128] = combined[b * 256 + tid + 128];
    __syncthreads();
    const float* W = (tid < 64) ? Wmu : Wlv;
    int l = tid & 63;
    float s = (tid < 64) ? bmu[l] : blv[l];
    for (int j = 0; j < 256; ++j) s += cb[j] * W[l * 256 + j];
    out[(tid < 64 ? 0 : BATCH * 64) + b * 64 + l] = s;
}

extern "C" void kernel_launch(void* const* d_in, const int* in_sizes, int n_in,
                              void* d_out, int out_size, void* d_ws, size_t ws_size,
                              hipStream_t stream) {
    const int* children = (const int*)d_in[2];
    const float* Wmu = (const float*)d_in[11];
    const float* bmu = (const float*)d_in[12];
    const float* Wlv = (const float*)d_in[13];
    const float* blv = (const float*)d_in[14];

    // ---- workspace layout (256B aligned) ----
    char* ws = (char*)d_ws;
    size_t off = 0;
    auto alloc = [&](size_t bytes) { void* p = ws + off; off += (bytes + 255) & ~(size_t)255; return p; };
    float* sums = (float*)alloc(2 * 2 * BATCH * 2 * sizeof(float));  // [layer][enc*B+b][2]
    float* msbuf = (float*)alloc(2 * 2 * BATCH * 2 * sizeof(float));
    float* combined = (float*)alloc((size_t)BATCH * 256 * sizeof(float));
    float* pool_part = (float*)alloc((size_t)2 * BATCH * 32 * HID * sizeof(float));
    __hip_bfloat16* Wp1 = (__hip_bfloat16*)alloc((size_t)2 * 3 * CIN * HID * sizeof(__hip_bfloat16));
    __hip_bfloat16* Wp2 = (__hip_bfloat16*)alloc((size_t)2 * 3 * HID * HID * sizeof(__hip_bfloat16));
    __hip_bfloat16* fT = (__hip_bfloat16*)alloc((size_t)2 * BATCH * NODES * CIN * sizeof(__hip_bfloat16));
    __hip_bfloat16* y1 = (__hip_bfloat16*)alloc((size_t)2 * BATCH * NODES * HID * sizeof(__hip_bfloat16));

    hipMemsetAsync(sums, 0, 2 * 2 * BATCH * 2 * sizeof(float), stream);

    k_wprep<<<dim3(3 * CIN * HID / 8 / 256, 2), 256, 0, stream>>>(
        (const float*)d_in[3], (const float*)d_in[7], Wp1, CIN);
    k_wprep<<<dim3(3 * HID * HID / 8 / 256, 2), 256, 0, stream>>>(
        (const float*)d_in[5], (const float*)d_in[9], Wp2, HID);
    k_transpose<<<dim3(129, 2, 2 * BATCH), dim3(32, 8), 0, stream>>>(
        (const float*)d_in[0], (const float*)d_in[1], fT);

    k_conv_mfma<CIN, false><<<4096, 256, 0, stream>>>(
        fT, children, Wp1, (const float*)d_in[4], (const float*)d_in[8], y1, sums, nullptr);
    k_stats<<<1, 128, 0, stream>>>(sums, msbuf);
    k_norm<<<dim3((NODES * HID / 8 + 255) / 256, 2 * BATCH), 256, 0, stream>>>(y1, msbuf);
    k_conv_mfma<HID, true><<<4096, 256, 0, stream>>>(
        y1, children, Wp2, (const float*)d_in[6], (const float*)d_in[10], nullptr,
        sums + 256, pool_part);
    k_stats<<<1, 128, 0, stream>>>(sums + 256, msbuf + 256);
    k_pool_fin<<<dim3(BATCH, 2), 128, 0, stream>>>(pool_part, msbuf + 256, combined);

    k_fc<<<BATCH, 128, 0, stream>>>(combined, Wmu, bmu, Wlv, blv, (float*)d_out);
}

// Round 8
// 404.296 us; speedup vs baseline: 1.2022x; 1.1430x over previous
//
#include <hip/hip_runtime.h>
#include <hip/hip_bf16.h>

#define NODES 4097
#define TT 4096
#define CIN 64
#define HID 128
#define BATCH 64
#define EPS 1e-5f

typedef short bf16x8 __attribute__((ext_vector_type(8)));   // 8 bf16 = 4 VGPRs
typedef float f32x16 __attribute__((ext_vector_type(16)));  // 32x32 acc

// async global->LDS DMA, 16 B per lane; LDS dst = wave-uniform base + lane*16
__device__ __forceinline__ void load_lds16(const void* g, void* l) {
    __builtin_amdgcn_global_load_lds(
        (const __attribute__((address_space(1))) unsigned int*)(uintptr_t)g,
        (__attribute__((address_space(3))) unsigned int*)(uintptr_t)l,
        16, 0, 0);
}

// ---------------- transpose feats (B,C,N) fp32 -> fT (B,N,C) bf16, both encoders ----------------
__global__ __launch_bounds__(256) void k_transpose(const float* __restrict__ f0,
                                                   const float* __restrict__ f1,
                                                   __hip_bfloat16* __restrict__ out) {
    __shared__ float tile[32][33];
    int z = blockIdx.z;
    int enc = z >> 6, b = z & 63;
    const float* in = enc ? f1 : f0;
    __hip_bfloat16* o = out + (size_t)enc * BATCH * NODES * CIN;
    int n0 = blockIdx.x * 32;
    int c0 = blockIdx.y * 32;
    int tx = threadIdx.x, ty = threadIdx.y;  // (32,8)
    for (int i = 0; i < 32; i += 8) {
        int n = n0 + tx, c = c0 + ty + i;
        float v = 0.f;
        if (n < NODES) v = in[((size_t)b * CIN + c) * NODES + n];
        tile[ty + i][tx] = v;
    }
    __syncthreads();
    for (int i = 0; i < 32; i += 8) {
        int n = n0 + ty + i, c = c0 + tx;
        if (n < NODES) o[((size_t)b * NODES + n) * CIN + c] = __float2bfloat16(tile[tx][ty + i]);
    }
}

// ---------------- W (HID,C,3) fp32 -> frag-major bf16 B-operand layout, both encoders ----------------
// Wp id = (ks*4 + ct)*64 + lane holds 8 bf16: B[k=ks*16+(lane>>5)*8+j][n=ct*32+(lane&31)]
// k = slot*C + c; B[k][n] = W[(n*C + c)*3 + slot]
__global__ void k_wprep(const float* __restrict__ W0, const float* __restrict__ W1,
                        __hip_bfloat16* __restrict__ Wp, int C) {
    int enc = blockIdx.y;
    const float* W = enc ? W1 : W0;
    __hip_bfloat16* o = Wp + (size_t)enc * 3 * C * HID;
    int id = blockIdx.x * 256 + threadIdx.x;
    int total = 3 * C * HID / 8;
    if (id >= total) return;
    int lane = id & 63;
    int ct = (id >> 6) & 3;
    int ks = id >> 8;
    int n = ct * 32 + (lane & 31);
    int kb = ks * 16 + (lane >> 5) * 8;
    union { int4 i; __hip_bfloat16 h[8]; } u;
#pragma unroll
    for (int j = 0; j < 8; ++j) {
        int k = kb + j;
        int slot = k / C, c = k % C;
        u.h[j] = __float2bfloat16(W[(n * C + c) * 3 + slot]);
    }
    ((int4*)o)[id] = u.i;
}

// ---------------- gather-conv via MFMA: B in LDS, A prefetched to registers ----------------
// Grid 4096 XCD-swizzled (xcd=L&7, node-tile fastest, b=xcd+8*bg pinned per XCD).
// Block = 4 waves, tile 128 nodes x 128 o; wave w covers nodes [t0+32w, +32), all o.
// Per phase (12 ksteps): stage 48 KB of frag-major Wp via contiguous global_load_lds,
// prefetch the phase's 12 A-frags (per-lane 16B gathers) into registers BEFORE the
// barrier (latency hides under the B drain); the MFMA loop then reads B via
// ds_read_b128 (conflict-free, lgkmcnt-pipelined) with zero global loads.
template <int C, bool POOL>
__global__ __launch_bounds__(256) void k_conv_mfma(
    const __hip_bfloat16* __restrict__ xT,    // [2][B][N][C]
    const int* __restrict__ children,
    const __hip_bfloat16* __restrict__ Wp,    // [2][3C*HID] frag-major
    const float* __restrict__ bias0, const float* __restrict__ bias1,
    __hip_bfloat16* __restrict__ y,           // [2][B][N][HID] raw out (if !POOL)
    float* __restrict__ sums,                 // [2B][2]
    float* __restrict__ pool_part) {          // [2B][32][HID] (if POOL)
    constexpr int KSc = C / 16;             // ksteps per child-slot (4 or 8)
    constexpr int KS = 3 * KSc;             // 12 or 24 ksteps total
    constexpr int PK = 12;                  // ksteps per phase
    constexpr int PH = KS / PK;             // 1 or 2 phases
    // ---- XCD-aware swizzle ----
    int L = blockIdx.x;
    int xcd = L & 7;
    int idx = L >> 3;
    int xt = idx & 31;              // node-tile (fastest within XCD)
    int bg = (idx >> 5) & 7;
    int enc = idx >> 8;
    int b = xcd + 8 * bg;           // b pinned to one XCD -> gather set stays in L2
    const int t0 = xt * 128;
    const int tid = threadIdx.x;
    const int lane = tid & 63;
    const int w = tid >> 6;
    const int hi = lane >> 5;

    __shared__ __align__(16) int4 B_lds[PK * 4 * 64];  // 48 KB, chunk c = (kk*4+cti)

    const __hip_bfloat16* x = xT + (size_t)enc * BATCH * NODES * C;
    const int4* WpB = (const int4*)(Wp + (size_t)enc * 3 * C * HID);
    const float* bias = enc ? bias1 : bias0;
    const int sb = enc * BATCH + b;
    const size_t rowbase = (size_t)b * NODES;
    const long cb3 = (long)b * (3 * TT);
    const int tnode = t0 + w * 32 + (lane & 31);  // node this lane's A-frags cover

    // gathered-row pointers, offset by this lane's k-octet half
    const int4* ap[3];
#pragma unroll
    for (int s = 0; s < 3; ++s) {
        int child = children[cb3 + (long)tnode * 3 + s];
        ap[s] = (const int4*)(x + (rowbase + child) * C) + hi;
    }

    f32x16 acc[4] = {};
#pragma unroll
    for (int ph = 0; ph < PH; ++ph) {
        if (ph) __syncthreads();  // prior phase's ds_reads done before overwrite
        // ---- stage this phase's B (48 KB, contiguous, coalesced) ----
#pragma unroll
        for (int i = 0; i < PK; ++i) {
            int chunk = w * PK + i;
            load_lds16(WpB + (size_t)(ph * PK * 4 + chunk) * 64 + lane, B_lds + chunk * 64);
        }
        // ---- prefetch this phase's A-frags into registers (hide under B drain) ----
        int4 areg[PK];
#pragma unroll
        for (int kk = 0; kk < PK; ++kk) {
            int ksg = ph * PK + kk;
            areg[kk] = ap[ksg / KSc][(ksg % KSc) * 2];
        }
        __syncthreads();  // drains DMA + A-gathers (vmcnt 0) + barrier
        // ---- MFMA loop: zero global loads ----
#pragma unroll
        for (int kk = 0; kk < PK; ++kk) {
            union { int4 i; bf16x8 v; } a;
            a.i = areg[kk];
#pragma unroll
            for (int cti = 0; cti < 4; ++cti) {
                union { int4 i; bf16x8 v; } bb;
                bb.i = B_lds[(kk * 4 + cti) * 64 + lane];
                acc[cti] = __builtin_amdgcn_mfma_f32_32x32x16_bf16(a.v, bb.v, acc[cti], 0, 0, 0);
            }
        }
    }

    __syncthreads();  // all ds_reads done; overlay reduction scratch on B_lds
    float* red = (float*)B_lds;          // [0..511] sum/sumsq
    float* pm = red + 512;               // [512..1535] 8 slices x 128 o, o-major
    float bsum = 0.f, bss = 0.f;
    __hip_bfloat16* yp = POOL ? nullptr : (y + (size_t)enc * BATCH * NODES * HID);
    const int rbase = t0 + w * 32 + 4 * hi + 1;  // +1: node-0 shift
#pragma unroll
    for (int cti = 0; cti < 4; ++cti) {
        int o = cti * 32 + (lane & 31);
        float bv = bias[o];
        f32x16 a = acc[cti];
        float lmax = -3.4e38f;
#pragma unroll
        for (int reg = 0; reg < 16; ++reg) {
            float v = a[reg] + bv;
            bsum += v;
            bss += v * v;
            if (POOL) {
                lmax = fmaxf(lmax, v);
            } else {
                int row = rbase + (reg & 3) + 8 * (reg >> 2);
                yp[(rowbase + row) * HID + o] = __float2bfloat16(v);
            }
        }
        if (POOL) pm[(w * 2 + hi) * 128 + o] = lmax;  // o consecutive per lane: no conflicts
    }
    if (!POOL && xt == 0 && tid < HID)
        yp[rowbase * HID + tid] = __float2bfloat16(0.f);

    red[tid] = bsum;
    red[256 + tid] = bss;
    __syncthreads();
    for (int s2 = 128; s2 > 0; s2 >>= 1) {
        if (tid < s2) { red[tid] += red[tid + s2]; red[256 + tid] += red[256 + tid + s2]; }
        __syncthreads();
    }
    if (tid == 0) {
        atomicAdd(&sums[sb * 2], red[0]);
        atomicAdd(&sums[sb * 2 + 1], red[256]);
    }
    if (POOL && tid < HID) {
        float m = -3.4e38f;
#pragma unroll
        for (int s2 = 0; s2 < 8; ++s2) m = fmaxf(m, pm[s2 * 128 + tid]);
        pool_part[((size_t)sb * 32 + xt) * HID + tid] = m;
    }
}

// ---------------- per-(enc,b) stats: sum,sumsq -> mean, 1/(std+eps) ----------------
__global__ void k_stats(const float* __restrict__ sums, float* __restrict__ ms) {
    int s = threadIdx.x;  // 128 = 2 enc x 64 b
    const float M = (float)HID * (float)NODES;
    float S = sums[s * 2], SS = sums[s * 2 + 1];
    float mean = S / M;
    float var = (SS - S * S / M) / (M - 1.f);
    float sd = sqrtf(fmaxf(var, 0.f));
    ms[s * 2] = mean;
    ms[s * 2 + 1] = 1.f / (sd + EPS);
}

// ---------------- in-place norm+relu of y1 (bf16 x8 vectorized) ----------------
__global__ __launch_bounds__(256) void k_norm(__hip_bfloat16* __restrict__ y,
                                              const float* __restrict__ ms) {
    constexpr int Q = NODES * HID / 8;  // 65552 int4s per (enc,b) slice
    int s = blockIdx.y;                 // enc*64 + b
    int q = blockIdx.x * 256 + threadIdx.x;
    if (q >= Q) return;
    float mean = ms[s * 2], scale = ms[s * 2 + 1];
    int4* p = (int4*)(y + (size_t)s * NODES * HID) + q;
    union { int4 i; __hip_bfloat16 h[8]; } u;
    u.i = *p;
#pragma unroll
    for (int j = 0; j < 8; ++j) {
        float f = (__bfloat162float(u.h[j]) - mean) * scale;
        u.h[j] = __float2bfloat16(f > 0.f ? f : 0.f);
    }
    *p = u.i;
}

// ---------------- finalize pool: reduce 32 partials, norm+relu ----------------
__global__ __launch_bounds__(128) void k_pool_fin(const float* __restrict__ part,
                                                  const float* __restrict__ ms1,
                                                  float* __restrict__ combined) {
    int b = blockIdx.x, enc = blockIdx.y, o = threadIdx.x;
    int sb = enc * BATCH + b;
    float m = 0.f;  // node-0 raw value is 0
#pragma unroll 4
    for (int s = 0; s < 32; ++s)
        m = fmaxf(m, part[((size_t)sb * 32 + s) * HID + o]);
    float v = (m - ms1[sb * 2]) * ms1[sb * 2 + 1];  // monotone: max then transform
    combined[b * 256 + enc * 128 + o] = v > 0.f ? v : 0.f;
}

// ---------------- final FC: mu / logvar ----------------
__global__ __launch_bounds__(128) void k_fc(const float* __restrict__ combined,
                                            const float* __restrict__ Wmu, const float* __restrict__ bmu,
                                            const float* __restrict__ Wlv, const float* __restrict__ blv,
                                            float* __restrict__ out) {
    int b = blockIdx.x;
    int tid = threadIdx.x;
    __shared__ float cb[256];
    cb[tid] = combined[b * 256 + tid];
    cb[tid + 128] = combined[b * 256 + tid + 128];
    __syncthreads();
    const float* W = (tid < 64) ? Wmu : Wlv;
    int l = tid & 63;
    float s = (tid < 64) ? bmu[l] : blv[l];
    for (int j = 0; j < 256; ++j) s += cb[j] * W[l * 256 + j];
    out[(tid < 64 ? 0 : BATCH * 64) + b * 64 + l] = s;
}

extern "C" void kernel_launch(void* const* d_in, const int* in_sizes, int n_in,
                              void* d_out, int out_size, void* d_ws, size_t ws_size,
                              hipStream_t stream) {
    const int* children = (const int*)d_in[2];
    const float* Wmu = (const float*)d_in[11];
    const float* bmu = (const float*)d_in[12];
    const float* Wlv = (const float*)d_in[13];
    const float* blv = (const float*)d_in[14];

    // ---- workspace layout (256B aligned) ----
    char* ws = (char*)d_ws;
    size_t off = 0;
    auto alloc = [&](size_t bytes) { void* p = ws + off; off += (bytes + 255) & ~(size_t)255; return p; };
    float* sums = (float*)alloc(2 * 2 * BATCH * 2 * sizeof(float));  // [layer][enc*B+b][2]
    float* msbuf = (float*)alloc(2 * 2 * BATCH * 2 * sizeof(float));
    float* combined = (float*)alloc((size_t)BATCH * 256 * sizeof(float));
    float* pool_part = (float*)alloc((size_t)2 * BATCH * 32 * HID * sizeof(float));
    __hip_bfloat16* Wp1 = (__hip_bfloat16*)alloc((size_t)2 * 3 * CIN * HID * sizeof(__hip_bfloat16));
    __hip_bfloat16* Wp2 = (__hip_bfloat16*)alloc((size_t)2 * 3 * HID * HID * sizeof(__hip_bfloat16));
    __hip_bfloat16* fT = (__hip_bfloat16*)alloc((size_t)2 * BATCH * NODES * CIN * sizeof(__hip_bfloat16));
    __hip_bfloat16* y1 = (__hip_bfloat16*)alloc((size_t)2 * BATCH * NODES * HID * sizeof(__hip_bfloat16));

    hipMemsetAsync(sums, 0, 2 * 2 * BATCH * 2 * sizeof(float), stream);

    k_wprep<<<dim3(3 * CIN * HID / 8 / 256, 2), 256, 0, stream>>>(
        (const float*)d_in[3], (const float*)d_in[7], Wp1, CIN);
    k_wprep<<<dim3(3 * HID * HID / 8 / 256, 2), 256, 0, stream>>>(
        (const float*)d_in[5], (const float*)d_in[9], Wp2, HID);
    k_transpose<<<dim3(129, 2, 2 * BATCH), dim3(32, 8), 0, stream>>>(
        (const float*)d_in[0], (const float*)d_in[1], fT);

    k_conv_mfma<CIN, false><<<4096, 256, 0, stream>>>(
        fT, children, Wp1, (const float*)d_in[4], (const float*)d_in[8], y1, sums, nullptr);
    k_stats<<<1, 128, 0, stream>>>(sums, msbuf);
    k_norm<<<dim3((NODES * HID / 8 + 255) / 256, 2 * BATCH), 256, 0, stream>>>(y1, msbuf);
    k_conv_mfma<HID, true><<<4096, 256, 0, stream>>>(
        y1, children, Wp2, (const float*)d_in[6], (const float*)d_in[10], nullptr,
        sums + 256, pool_part);
    k_stats<<<1, 128, 0, stream>>>(sums + 256, msbuf + 256);
    k_pool_fin<<<dim3(BATCH, 2), 128, 0, stream>>>(pool_part, msbuf + 256, combined);

    k_fc<<<BATCH, 128, 0, stream>>>(combined, Wmu, bmu, Wlv, blv, (float*)d_out);
}